// Round 14
// baseline (179.043 us; speedup 1.0000x reference)
//
#include <hip/hip_runtime.h>
#include <hip/hip_bf16.h>

#define BB   128
#define CIN  9
#define TT   2048
#define RR   512
#define NN   (BB*RR)     // 65536
#define HID  128
#define NOUT 12

typedef __attribute__((ext_vector_type(8))) short short8;
typedef __attribute__((ext_vector_type(4))) float f32x4;

static __device__ inline unsigned short f2bf(float f) {       // RNE f32->bf16
    unsigned int u = __float_as_uint(f);
    unsigned int r = (u + 0x7fffu + ((u >> 16) & 1u)) >> 16;
    return (unsigned short)r;
}
static __device__ inline float bf2f(unsigned short u) {
    return __uint_as_float(((unsigned int)u) << 16);
}

// =======================================================================
// Block 0: per-sample CSR build (starts first, overlaps the conv blocks).
// Blocks 1..1024: fused conv1+relu+pool2 -> conv2+relu+pool2 -> nodes bf16.
// [byte-identical to R12]
// =======================================================================
__global__ __launch_bounds__(512) void k_convs(const float* __restrict__ x,
        const float* __restrict__ w1, const float* __restrict__ b1,
        const float* __restrict__ w2, const float* __restrict__ b2,
        unsigned short* __restrict__ nodes16,
        const int* __restrict__ ei, int E, int es,
        int* __restrict__ rptr, float* __restrict__ dis, int* __restrict__ adj) {
    __shared__ float sx[CIN][268];     // x tile
    __shared__ float s1[16][132];      // pooled conv1
    __shared__ int lcnt[512];
    __shared__ int sp[512];
    __shared__ int lcur[512];
    int tid = threadIdx.x;

    if (blockIdx.x == 0) {
        // ---- CSR build for the per-sample graph ----
        int t = tid;
        lcnt[t] = 0;
        __syncthreads();
        for (int i = t; i < es; i += 512) atomicAdd(&lcnt[ei[E + i]], 1);
        __syncthreads();
        int c = lcnt[t];
        sp[t] = c;
        __syncthreads();
        for (int off = 1; off < 512; off <<= 1) {
            int v = sp[t];
            int add = (t >= off) ? sp[t - off] : 0;
            __syncthreads();
            sp[t] = v + add;
            __syncthreads();
        }
        int excl = sp[t] - c;
        rptr[t] = excl;
        if (t == 511) rptr[512] = es;
        dis[t] = rsqrtf((float)c + 1.0f);
        lcur[t] = excl;
        __syncthreads();
        for (int i = t; i < es; i += 512) {
            int row = ei[i], col = ei[E + i];
            int pos = atomicAdd(&lcur[col], 1);
            adj[pos] = row;
        }
        return;
    }

    int cb = blockIdx.x - 1;
    int b  = cb >> 3;
    int r0 = (cb & 7) * 64;
    int wv   = __builtin_amdgcn_readfirstlane(tid >> 6);   // wave 0..7
    int lane = tid & 63;

    for (int idx = tid; idx < CIN * 268; idx += 512) {
        int c = idx / 268, j = idx - c * 268;
        int g = 4 * r0 - 6 + j;
        float v = 0.f;
        if (g >= 0 && g < TT) v = x[(b * CIN + c) * TT + g];
        sx[c][j] = v;
    }
    __syncthreads();

    // phase B: wave wv covers channels wv*2, wv*2+1 (x window read once, cc-inner)
    {
        int c1a = wv * 2, c1b = wv * 2 + 1;
        float biasA = b1[c1a], biasB = b1[c1b];
        for (int pp = lane; pp < 132; pp += 64) {
            int p = 2 * r0 - 2 + pp;
            float valA = 0.f, valB = 0.f;
            if (p >= 0 && p < 1024) {
                float a0A = biasA, a1A = biasA, a0B = biasB, a1B = biasB;
#pragma unroll
                for (int c = 0; c < CIN; ++c) {
                    const float2* px = (const float2*)&sx[c][2 * pp];
                    float2 q0 = px[0], q1 = px[1], q2 = px[2];
                    {
                        const float* wp = &w1[(c1a * CIN + c) * 5];
                        float k0 = wp[0], k1 = wp[1], k2 = wp[2], k3 = wp[3], k4 = wp[4];
                        a0A += q0.x*k0 + q0.y*k1 + q1.x*k2 + q1.y*k3 + q2.x*k4;
                        a1A += q0.y*k0 + q1.x*k1 + q1.y*k2 + q2.x*k3 + q2.y*k4;
                    }
                    {
                        const float* wp = &w1[(c1b * CIN + c) * 5];
                        float k0 = wp[0], k1 = wp[1], k2 = wp[2], k3 = wp[3], k4 = wp[4];
                        a0B += q0.x*k0 + q0.y*k1 + q1.x*k2 + q1.y*k3 + q2.x*k4;
                        a1B += q0.y*k0 + q1.x*k1 + q1.y*k2 + q2.x*k3 + q2.y*k4;
                    }
                }
                valA = fmaxf(fmaxf(a0A, a1A), 0.f);
                valB = fmaxf(fmaxf(a0B, a1B), 0.f);
            }
            s1[c1a][pp] = valA;
            s1[c1b][pp] = valB;
        }
    }
    __syncthreads();

    // phase C: wave wv covers channels wv*4..wv*4+3 -> nodes16 bf16
    int rl = lane;
    float acc0[4], acc1[4];
#pragma unroll
    for (int o = 0; o < 4; ++o) {
        float bv = b2[wv * 4 + o];
        acc0[o] = bv; acc1[o] = bv;
    }
#pragma unroll
    for (int c = 0; c < 16; ++c) {
        const float2* ps = (const float2*)&s1[c][2 * rl];
        float2 q0 = ps[0], q1 = ps[1], q2 = ps[2];
#pragma unroll
        for (int o = 0; o < 4; ++o) {
            const float* wp = &w2[((wv * 4 + o) * 16 + c) * 5];
            float k0 = wp[0], k1 = wp[1], k2 = wp[2], k3 = wp[3], k4 = wp[4];
            acc0[o] += q0.x*k0 + q0.y*k1 + q1.x*k2 + q1.y*k3 + q2.x*k4;
            acc1[o] += q0.y*k0 + q1.x*k1 + q1.y*k2 + q2.x*k3 + q2.y*k4;
        }
    }
    int n = b * RR + r0 + rl;
    ushort4 ov;
    ov.x = f2bf(fmaxf(fmaxf(acc0[0], acc1[0]), 0.f));
    ov.y = f2bf(fmaxf(fmaxf(acc0[1], acc1[1]), 0.f));
    ov.z = f2bf(fmaxf(fmaxf(acc0[2], acc1[2]), 0.f));
    ov.w = f2bf(fmaxf(fmaxf(acc0[3], acc1[3]), 0.f));
    *(ushort4*)&nodes16[n * 32 + wv * 4] = ov;
}

// =======================================================================
// Fused layer-1: gather on 32-dim bf16 + lin1 + bias + relu -> h1 (bf16) [R12]
// =======================================================================
__global__ __launch_bounds__(256) void k_gl1(const int* __restrict__ rptr,
        const int* __restrict__ adj, const float* __restrict__ dis,
        const unsigned short* __restrict__ nodes16, const float* __restrict__ w,
        const float* __restrict__ bias, unsigned short* __restrict__ h16) {
    __shared__ float srow[32][32];
    __shared__ float sw[32 * 128];
    int bid = (blockIdx.x & 7) * 256 + (blockIdx.x >> 3);   // XCD swizzle, 2048
    int tid = threadIdx.x;
    int nbase = bid * 32;
    int b = nbase >> 9;
    const unsigned short* hb = nodes16 + (size_t)b * RR * 32;

    {   // weights -> LDS
        const float4* src = (const float4*)w;
        float4* dst = (float4*)sw;
#pragma unroll
        for (int i = 0; i < 4; ++i) dst[tid + i * 256] = src[tid + i * 256];
    }

    int ln   = tid >> 3;
    int lane = tid & 7;
    int r = (nbase & 511) + ln;
    int s = rptr[r], e = rptr[r + 1];
    float dn = dis[r];
    float4 acc = make_float4(0.f, 0.f, 0.f, 0.f);
    for (int base = s; base < e; base += 8) {
        int j = base + lane;
        int src = 0; float nd = 0.f;
        if (j < e) { src = adj[j]; nd = dis[src]; }
        int cnt = min(8, e - base);
        int k = 0;
        for (; k + 4 <= cnt; k += 4) {
            int   s0 = __shfl(src, k, 8),     s1 = __shfl(src, k + 1, 8);
            int   s2 = __shfl(src, k + 2, 8), s3 = __shfl(src, k + 3, 8);
            float n0 = __shfl(nd, k, 8),      n1 = __shfl(nd, k + 1, 8);
            float n2 = __shfl(nd, k + 2, 8),  n3 = __shfl(nd, k + 3, 8);
            ushort4 u0 = *(const ushort4*)&hb[(size_t)s0 * 32 + lane * 4];
            ushort4 u1 = *(const ushort4*)&hb[(size_t)s1 * 32 + lane * 4];
            ushort4 u2 = *(const ushort4*)&hb[(size_t)s2 * 32 + lane * 4];
            ushort4 u3 = *(const ushort4*)&hb[(size_t)s3 * 32 + lane * 4];
            float w0 = dn * n0, w1 = dn * n1, w2 = dn * n2, w3 = dn * n3;
            acc.x += w0*bf2f(u0.x) + w1*bf2f(u1.x) + w2*bf2f(u2.x) + w3*bf2f(u3.x);
            acc.y += w0*bf2f(u0.y) + w1*bf2f(u1.y) + w2*bf2f(u2.y) + w3*bf2f(u3.y);
            acc.z += w0*bf2f(u0.z) + w1*bf2f(u1.z) + w2*bf2f(u2.z) + w3*bf2f(u3.z);
            acc.w += w0*bf2f(u0.w) + w1*bf2f(u1.w) + w2*bf2f(u2.w) + w3*bf2f(u3.w);
        }
        for (; k < cnt; ++k) {
            int   sk = __shfl(src, k, 8);
            float nk = __shfl(nd, k, 8);
            ushort4 u = *(const ushort4*)&hb[(size_t)sk * 32 + lane * 4];
            float wgt = dn * nk;
            acc.x += wgt * bf2f(u.x); acc.y += wgt * bf2f(u.y);
            acc.z += wgt * bf2f(u.z); acc.w += wgt * bf2f(u.w);
        }
    }
    {   // self loop
        ushort4 u = *(const ushort4*)&hb[(size_t)r * 32 + lane * 4];
        float wgt = dn * dn;
        acc.x += wgt * bf2f(u.x); acc.y += wgt * bf2f(u.y);
        acc.z += wgt * bf2f(u.z); acc.w += wgt * bf2f(u.w);
    }
    *(float4*)&srow[ln][lane * 4] = acc;
    __syncthreads();

    int fq = tid & 31;
    int ng = tid >> 5;
    float a[4][4];
#pragma unroll
    for (int j = 0; j < 4; ++j)
#pragma unroll
        for (int q = 0; q < 4; ++q) a[j][q] = 0.f;
#pragma unroll
    for (int c = 0; c < 32; ++c) {
        float4 wvv = *(const float4*)&sw[c * 128 + fq * 4];
#pragma unroll
        for (int j = 0; j < 4; ++j) {
            float xc = srow[ng * 4 + j][c];
            a[j][0] += xc * wvv.x; a[j][1] += xc * wvv.y;
            a[j][2] += xc * wvv.z; a[j][3] += xc * wvv.w;
        }
    }
    float4 bv = *(const float4*)&bias[fq * 4];
#pragma unroll
    for (int j = 0; j < 4; ++j) {
        ushort4 o;
        o.x = f2bf(fmaxf(a[j][0] + bv.x, 0.f));
        o.y = f2bf(fmaxf(a[j][1] + bv.y, 0.f));
        o.z = f2bf(fmaxf(a[j][2] + bv.z, 0.f));
        o.w = f2bf(fmaxf(a[j][3] + bv.w, 0.f));
        *(ushort4*)&h16[(size_t)(nbase + ng * 4 + j) * 128 + fq * 4] = o;
    }
}

// =======================================================================
// lin2 via MFMA bf16: h2[N,128] = h1[N,128] @ W[128,128]   [R12]
// =======================================================================
__global__ __launch_bounds__(256) void k_lin2(const unsigned short* __restrict__ g16,
        const float* __restrict__ w, unsigned short* __restrict__ h16) {
    __shared__ unsigned short srow[64][136];
    __shared__ unsigned short swT[128][136];
    int tid = threadIdx.x;
    int nbase = blockIdx.x * 64;

    {
        const ushort4* src = (const ushort4*)(g16 + (size_t)nbase * 128);
#pragma unroll
        for (int i = 0; i < 8; ++i) {
            int idx = tid + i * 256;
            int row = idx >> 5, col4 = idx & 31;
            ushort4 v = src[idx];
            *(ushort4*)&srow[row][col4 * 4] = v;
        }
    }
    {
        for (int i = 0; i < 64; ++i) {
            int idx = i * 256 + tid;
            int c = idx >> 7, f = idx & 127;
            swT[f][c] = f2bf(w[idx]);
        }
    }
    __syncthreads();

    int wv  = tid >> 6;
    int lane = tid & 63;
    int m0 = wv * 16;
    int l15 = lane & 15;
    int quad = lane >> 4;
    f32x4 acc[8];
#pragma unroll
    for (int nt = 0; nt < 8; ++nt) acc[nt] = (f32x4){0.f, 0.f, 0.f, 0.f};
#pragma unroll
    for (int kc = 0; kc < 4; ++kc) {
        int k0 = kc * 32 + quad * 8;
        short8 a = *(const short8*)&srow[m0 + l15][k0];
#pragma unroll
        for (int nt = 0; nt < 8; ++nt) {
            short8 b = *(const short8*)&swT[nt * 16 + l15][k0];
            acc[nt] = __builtin_amdgcn_mfma_f32_16x16x32_bf16(a, b, acc[nt], 0, 0, 0);
        }
    }
#pragma unroll
    for (int nt = 0; nt < 8; ++nt) {
#pragma unroll
        for (int r = 0; r < 4; ++r) {
            int row = m0 + quad * 4 + r;
            int col = nt * 16 + l15;
            h16[(size_t)(nbase + row) * 128 + col] = f2bf(acc[nt][r]);
        }
    }
}

// =======================================================================
// Layer-2 gather v2: 2 nodes per 32-lane group (independent chains for MLP),
// + self-loop + bias + relu + per-block mean partials. 16 nodes/block.
// =======================================================================
#define G128_STEP4(SRC, ND, ACC, KK)                                           \
    {                                                                          \
        int   t0 = __shfl(SRC, (KK), 32),     t1 = __shfl(SRC, (KK) + 1, 32);  \
        int   t2 = __shfl(SRC, (KK) + 2, 32), t3 = __shfl(SRC, (KK) + 3, 32);  \
        float m0 = __shfl(ND, (KK), 32),      m1 = __shfl(ND, (KK) + 1, 32);   \
        float m2 = __shfl(ND, (KK) + 2, 32),  m3 = __shfl(ND, (KK) + 3, 32);   \
        ushort4 u0 = *(const ushort4*)&hb[(size_t)t0 * 128 + lane * 4];        \
        ushort4 u1 = *(const ushort4*)&hb[(size_t)t1 * 128 + lane * 4];        \
        ushort4 u2 = *(const ushort4*)&hb[(size_t)t2 * 128 + lane * 4];        \
        ushort4 u3 = *(const ushort4*)&hb[(size_t)t3 * 128 + lane * 4];        \
        ACC.x += m0*bf2f(u0.x) + m1*bf2f(u1.x) + m2*bf2f(u2.x) + m3*bf2f(u3.x);\
        ACC.y += m0*bf2f(u0.y) + m1*bf2f(u1.y) + m2*bf2f(u2.y) + m3*bf2f(u3.y);\
        ACC.z += m0*bf2f(u0.z) + m1*bf2f(u1.z) + m2*bf2f(u2.z) + m3*bf2f(u3.z);\
        ACC.w += m0*bf2f(u0.w) + m1*bf2f(u1.w) + m2*bf2f(u2.w) + m3*bf2f(u3.w);\
    }
#define G128_STEP1(SRC, ND, ACC, KK)                                           \
    {                                                                          \
        int   tk = __shfl(SRC, (KK), 32);                                      \
        float mk = __shfl(ND, (KK), 32);                                       \
        ushort4 u = *(const ushort4*)&hb[(size_t)tk * 128 + lane * 4];         \
        ACC.x += mk * bf2f(u.x); ACC.y += mk * bf2f(u.y);                      \
        ACC.z += mk * bf2f(u.z); ACC.w += mk * bf2f(u.w);                      \
    }

__global__ __launch_bounds__(256) void k_gather128(const int* __restrict__ rptr,
        const int* __restrict__ adj, const float* __restrict__ dis,
        const unsigned short* __restrict__ h, const float* __restrict__ bias,
        float* __restrict__ partial) {
    __shared__ float sred[16][128];
    int bid  = (blockIdx.x & 7) * 512 + (blockIdx.x >> 3);   // XCD swizzle, 4096
    int tid  = threadIdx.x;
    int g    = tid >> 5;          // group 0..7
    int lane = tid & 31;
    int nodeA = bid * 16 + g * 2; // two nodes per group (same sample)
    int b = nodeA >> 9;
    int rA = nodeA & 511;
    int rB = rA + 1;
    const unsigned short* hb = h + (size_t)b * RR * 128;
    int sA = rptr[rA], eA = rptr[rA + 1];
    int sB = rptr[rB], eB = rptr[rB + 1];
    float dnA = dis[rA], dnB = dis[rB];
    float4 accA = make_float4(0.f, 0.f, 0.f, 0.f);
    float4 accB = make_float4(0.f, 0.f, 0.f, 0.f);

    int baseA = sA, baseB = sB;
    while (baseA < eA || baseB < eB) {
        int srcA = 0, srcB = 0;
        float ndA = 0.f, ndB = 0.f;
        int cntA = 0, cntB = 0;
        if (baseA < eA) {
            int j = baseA + lane;
            if (j < eA) { srcA = adj[j]; ndA = dnA * dis[srcA]; }
            cntA = min(32, eA - baseA);
        }
        if (baseB < eB) {
            int j = baseB + lane;
            if (j < eB) { srcB = adj[j]; ndB = dnB * dis[srcB]; }
            cntB = min(32, eB - baseB);
        }
        int c = min(cntA, cntB);
        int k = 0;
        for (; k + 4 <= c; k += 4) {          // interleaved: 8 loads in flight
            G128_STEP4(srcA, ndA, accA, k);
            G128_STEP4(srcB, ndB, accB, k);
        }
        int kA = k;
        for (; kA + 4 <= cntA; kA += 4) G128_STEP4(srcA, ndA, accA, kA);
        for (; kA < cntA; ++kA)         G128_STEP1(srcA, ndA, accA, kA);
        int kB = k;
        for (; kB + 4 <= cntB; kB += 4) G128_STEP4(srcB, ndB, accB, kB);
        for (; kB < cntB; ++kB)         G128_STEP1(srcB, ndB, accB, kB);
        baseA += 32;
        baseB += 32;
    }

    float4 bv = *(const float4*)&bias[lane * 4];
    {   // self loop + bias + relu, node A
        ushort4 u = *(const ushort4*)&hb[(size_t)rA * 128 + lane * 4];
        float wgt = dnA * dnA;
        accA.x = fmaxf(accA.x + wgt * bf2f(u.x) + bv.x, 0.f);
        accA.y = fmaxf(accA.y + wgt * bf2f(u.y) + bv.y, 0.f);
        accA.z = fmaxf(accA.z + wgt * bf2f(u.z) + bv.z, 0.f);
        accA.w = fmaxf(accA.w + wgt * bf2f(u.w) + bv.w, 0.f);
    }
    {   // self loop + bias + relu, node B
        ushort4 u = *(const ushort4*)&hb[(size_t)rB * 128 + lane * 4];
        float wgt = dnB * dnB;
        accB.x = fmaxf(accB.x + wgt * bf2f(u.x) + bv.x, 0.f);
        accB.y = fmaxf(accB.y + wgt * bf2f(u.y) + bv.y, 0.f);
        accB.z = fmaxf(accB.z + wgt * bf2f(u.z) + bv.z, 0.f);
        accB.w = fmaxf(accB.w + wgt * bf2f(u.w) + bv.w, 0.f);
    }
    *(float4*)&sred[g * 2][lane * 4]     = accA;
    *(float4*)&sred[g * 2 + 1][lane * 4] = accB;
    __syncthreads();
    if (tid < 128) {
        float ssum = 0.f;
#pragma unroll
        for (int j = 0; j < 16; ++j) ssum += sred[j][tid];
        partial[(size_t)bid * 128 + tid] = ssum;   // plain coalesced store
    }
}

// ---------------- fc: sum partials (32/sample) -> mean -> fc ----------------
__global__ __launch_bounds__(128) void k_fc(const float* __restrict__ partial,
        const float* __restrict__ fw, const float* __restrict__ fb,
        float* __restrict__ out) {
    __shared__ float sm[HID];
    int b = blockIdx.x, f = threadIdx.x;
    float acc = 0.f;
#pragma unroll 8
    for (int j = 0; j < 32; ++j) acc += partial[(size_t)(b * 32 + j) * 128 + f];
    sm[f] = acc * (1.0f / RR);
    __syncthreads();
    if (f < NOUT) {
        float s = fb[f];
#pragma unroll
        for (int c = 0; c < HID; ++c) s += sm[c] * fw[c * NOUT + f];
        out[b * NOUT + f] = s;
    }
}

extern "C" void kernel_launch(void* const* d_in, const int* in_sizes, int n_in,
                              void* d_out, int out_size, void* d_ws, size_t ws_size,
                              hipStream_t stream) {
    const float* x   = (const float*)d_in[0];
    const int*   ei  = (const int*)d_in[1];
    const float* c1w = (const float*)d_in[2];
    const float* c1b = (const float*)d_in[3];
    const float* c2w = (const float*)d_in[4];
    const float* c2b = (const float*)d_in[5];
    const float* g1w = (const float*)d_in[6];
    const float* g1b = (const float*)d_in[7];
    const float* g2w = (const float*)d_in[8];
    const float* g2b = (const float*)d_in[9];
    const float* fw  = (const float*)d_in[10];
    const float* fb  = (const float*)d_in[11];
    float* out = (float*)d_out;
    int E  = in_sizes[1] / 2;   // total edges (1048576)
    int es = E / BB;            // edges per sample graph (8192)

    char* ws = (char*)d_ws;
    unsigned short* nodes16 = (unsigned short*)(ws);               // 4 MB  [N,32] bf16
    unsigned short* bufA16  = (unsigned short*)(ws + (4u << 20));  // 16 MB [N,128] bf16
    unsigned short* bufC16  = (unsigned short*)(ws + (20u << 20)); // 16 MB [N,128] bf16
    int*   rptr    = (int*)  (ws + (36u << 20));                   // [513]
    float* dis     = (float*)(ws + (36u << 20) + 4096);            // [512]
    int*   adj     = (int*)  (ws + (36u << 20) + 8192);            // 32 KB [es]
    float* partial = (float*)(ws + (37u << 20));                   // 2 MB [4096,128]

    // CSR build (block 0, starts first) + fused temporal convs (blocks 1..1024)
    k_convs<<<BB * 8 + 1, 512, 0, stream>>>(x, c1w, c1b, c2w, c2b, nodes16,
                                            ei, E, es, rptr, dis, adj);

    // GCN layer 1: fused gather(32-dim bf16) + linear + bias + relu -> bf16
    k_gl1<<<NN / 32, 256, 0, stream>>>(rptr, adj, dis, nodes16, g1w, g1b, bufA16);

    // GCN layer 2: MFMA linear (bf16), then dual-node gather -> partials
    k_lin2<<<NN / 64, 256, 0, stream>>>(bufA16, g2w, bufC16);
    k_gather128<<<NN / 16, 256, 0, stream>>>(rptr, adj, dis, bufC16, g2b, partial);

    // mean (from partials) + fc
    k_fc<<<BB, 128, 0, stream>>>(partial, fw, fb, out);
}

// Round 15
// 170.798 us; speedup vs baseline: 1.0483x; 1.0483x over previous
//
#include <hip/hip_runtime.h>
#include <hip/hip_bf16.h>

#define BB   128
#define CIN  9
#define TT   2048
#define RR   512
#define NN   (BB*RR)     // 65536
#define HID  128
#define NOUT 12

typedef __attribute__((ext_vector_type(8))) short short8;
typedef __attribute__((ext_vector_type(4))) float f32x4;

static __device__ inline unsigned short f2bf(float f) {       // RNE f32->bf16
    unsigned int u = __float_as_uint(f);
    unsigned int r = (u + 0x7fffu + ((u >> 16) & 1u)) >> 16;
    return (unsigned short)r;
}
static __device__ inline float bf2f(unsigned short u) {
    return __uint_as_float(((unsigned int)u) << 16);
}

// =======================================================================
// Block 0: per-sample CSR build + W2^T bf16 precompute (starts first).
// Blocks 1..1024: fused conv1+relu+pool2 -> conv2+relu+pool2 -> nodes bf16.
// [conv path byte-identical to R12]
// =======================================================================
__global__ __launch_bounds__(512) void k_convs(const float* __restrict__ x,
        const float* __restrict__ w1, const float* __restrict__ b1,
        const float* __restrict__ w2, const float* __restrict__ b2,
        unsigned short* __restrict__ nodes16,
        const int* __restrict__ ei, int E, int es,
        int* __restrict__ rptr, float* __restrict__ dis, int* __restrict__ adj,
        const float* __restrict__ g2w, unsigned short* __restrict__ w2t) {
    __shared__ float sx[CIN][268];     // x tile
    __shared__ float s1[16][132];      // pooled conv1
    __shared__ int lcnt[512];
    __shared__ int sp[512];
    __shared__ int lcur[512];
    int tid = threadIdx.x;

    if (blockIdx.x == 0) {
        // ---- CSR build for the per-sample graph ----
        int t = tid;
        lcnt[t] = 0;
        __syncthreads();
        for (int i = t; i < es; i += 512) atomicAdd(&lcnt[ei[E + i]], 1);
        __syncthreads();
        int c = lcnt[t];
        sp[t] = c;
        __syncthreads();
        for (int off = 1; off < 512; off <<= 1) {
            int v = sp[t];
            int add = (t >= off) ? sp[t - off] : 0;
            __syncthreads();
            sp[t] = v + add;
            __syncthreads();
        }
        int excl = sp[t] - c;
        rptr[t] = excl;
        if (t == 511) rptr[512] = es;
        dis[t] = rsqrtf((float)c + 1.0f);
        lcur[t] = excl;
        __syncthreads();
        for (int i = t; i < es; i += 512) {
            int row = ei[i], col = ei[E + i];
            int pos = atomicAdd(&lcur[col], 1);
            adj[pos] = row;
        }
        // ---- W2^T bf16: w2t[f*128+c] = bf16(g2w[c*128+f]) ----
        for (int idx = t; idx < 128 * 128; idx += 512) {
            int c2 = idx >> 7, f = idx & 127;
            w2t[f * 128 + c2] = f2bf(g2w[idx]);
        }
        return;
    }

    int cb = blockIdx.x - 1;
    int b  = cb >> 3;
    int r0 = (cb & 7) * 64;
    int wv   = __builtin_amdgcn_readfirstlane(tid >> 6);   // wave 0..7
    int lane = tid & 63;

    for (int idx = tid; idx < CIN * 268; idx += 512) {
        int c = idx / 268, j = idx - c * 268;
        int g = 4 * r0 - 6 + j;
        float v = 0.f;
        if (g >= 0 && g < TT) v = x[(b * CIN + c) * TT + g];
        sx[c][j] = v;
    }
    __syncthreads();

    // phase B: wave wv covers channels wv*2, wv*2+1 (x window read once, cc-inner)
    {
        int c1a = wv * 2, c1b = wv * 2 + 1;
        float biasA = b1[c1a], biasB = b1[c1b];
        for (int pp = lane; pp < 132; pp += 64) {
            int p = 2 * r0 - 2 + pp;
            float valA = 0.f, valB = 0.f;
            if (p >= 0 && p < 1024) {
                float a0A = biasA, a1A = biasA, a0B = biasB, a1B = biasB;
#pragma unroll
                for (int c = 0; c < CIN; ++c) {
                    const float2* px = (const float2*)&sx[c][2 * pp];
                    float2 q0 = px[0], q1 = px[1], q2 = px[2];
                    {
                        const float* wp = &w1[(c1a * CIN + c) * 5];
                        float k0 = wp[0], k1 = wp[1], k2 = wp[2], k3 = wp[3], k4 = wp[4];
                        a0A += q0.x*k0 + q0.y*k1 + q1.x*k2 + q1.y*k3 + q2.x*k4;
                        a1A += q0.y*k0 + q1.x*k1 + q1.y*k2 + q2.x*k3 + q2.y*k4;
                    }
                    {
                        const float* wp = &w1[(c1b * CIN + c) * 5];
                        float k0 = wp[0], k1 = wp[1], k2 = wp[2], k3 = wp[3], k4 = wp[4];
                        a0B += q0.x*k0 + q0.y*k1 + q1.x*k2 + q1.y*k3 + q2.x*k4;
                        a1B += q0.y*k0 + q1.x*k1 + q1.y*k2 + q2.x*k3 + q2.y*k4;
                    }
                }
                valA = fmaxf(fmaxf(a0A, a1A), 0.f);
                valB = fmaxf(fmaxf(a0B, a1B), 0.f);
            }
            s1[c1a][pp] = valA;
            s1[c1b][pp] = valB;
        }
    }
    __syncthreads();

    // phase C: wave wv covers channels wv*4..wv*4+3 -> nodes16 bf16
    int rl = lane;
    float acc0[4], acc1[4];
#pragma unroll
    for (int o = 0; o < 4; ++o) {
        float bv = b2[wv * 4 + o];
        acc0[o] = bv; acc1[o] = bv;
    }
#pragma unroll
    for (int c = 0; c < 16; ++c) {
        const float2* ps = (const float2*)&s1[c][2 * rl];
        float2 q0 = ps[0], q1 = ps[1], q2 = ps[2];
#pragma unroll
        for (int o = 0; o < 4; ++o) {
            const float* wp = &w2[((wv * 4 + o) * 16 + c) * 5];
            float k0 = wp[0], k1 = wp[1], k2 = wp[2], k3 = wp[3], k4 = wp[4];
            acc0[o] += q0.x*k0 + q0.y*k1 + q1.x*k2 + q1.y*k3 + q2.x*k4;
            acc1[o] += q0.y*k0 + q1.x*k1 + q1.y*k2 + q2.x*k3 + q2.y*k4;
        }
    }
    int n = b * RR + r0 + rl;
    ushort4 ov;
    ov.x = f2bf(fmaxf(fmaxf(acc0[0], acc1[0]), 0.f));
    ov.y = f2bf(fmaxf(fmaxf(acc0[1], acc1[1]), 0.f));
    ov.z = f2bf(fmaxf(fmaxf(acc0[2], acc1[2]), 0.f));
    ov.w = f2bf(fmaxf(fmaxf(acc0[3], acc1[3]), 0.f));
    *(ushort4*)&nodes16[n * 32 + wv * 4] = ov;
}

// =======================================================================
// Fused layer-1: gather on 32-dim bf16 + lin1 + bias + relu -> h1 (bf16) [R12]
// =======================================================================
__global__ __launch_bounds__(256) void k_gl1(const int* __restrict__ rptr,
        const int* __restrict__ adj, const float* __restrict__ dis,
        const unsigned short* __restrict__ nodes16, const float* __restrict__ w,
        const float* __restrict__ bias, unsigned short* __restrict__ h16) {
    __shared__ float srow[32][32];
    __shared__ float sw[32 * 128];
    int bid = (blockIdx.x & 7) * 256 + (blockIdx.x >> 3);   // XCD swizzle, 2048
    int tid = threadIdx.x;
    int nbase = bid * 32;
    int b = nbase >> 9;
    const unsigned short* hb = nodes16 + (size_t)b * RR * 32;

    {   // weights -> LDS
        const float4* src = (const float4*)w;
        float4* dst = (float4*)sw;
#pragma unroll
        for (int i = 0; i < 4; ++i) dst[tid + i * 256] = src[tid + i * 256];
    }

    int ln   = tid >> 3;
    int lane = tid & 7;
    int r = (nbase & 511) + ln;
    int s = rptr[r], e = rptr[r + 1];
    float dn = dis[r];
    float4 acc = make_float4(0.f, 0.f, 0.f, 0.f);
    for (int base = s; base < e; base += 8) {
        int j = base + lane;
        int src = 0; float nd = 0.f;
        if (j < e) { src = adj[j]; nd = dis[src]; }
        int cnt = min(8, e - base);
        int k = 0;
        for (; k + 4 <= cnt; k += 4) {
            int   s0 = __shfl(src, k, 8),     s1 = __shfl(src, k + 1, 8);
            int   s2 = __shfl(src, k + 2, 8), s3 = __shfl(src, k + 3, 8);
            float n0 = __shfl(nd, k, 8),      n1 = __shfl(nd, k + 1, 8);
            float n2 = __shfl(nd, k + 2, 8),  n3 = __shfl(nd, k + 3, 8);
            ushort4 u0 = *(const ushort4*)&hb[(size_t)s0 * 32 + lane * 4];
            ushort4 u1 = *(const ushort4*)&hb[(size_t)s1 * 32 + lane * 4];
            ushort4 u2 = *(const ushort4*)&hb[(size_t)s2 * 32 + lane * 4];
            ushort4 u3 = *(const ushort4*)&hb[(size_t)s3 * 32 + lane * 4];
            float w0 = dn * n0, w1 = dn * n1, w2 = dn * n2, w3 = dn * n3;
            acc.x += w0*bf2f(u0.x) + w1*bf2f(u1.x) + w2*bf2f(u2.x) + w3*bf2f(u3.x);
            acc.y += w0*bf2f(u0.y) + w1*bf2f(u1.y) + w2*bf2f(u2.y) + w3*bf2f(u3.y);
            acc.z += w0*bf2f(u0.z) + w1*bf2f(u1.z) + w2*bf2f(u2.z) + w3*bf2f(u3.z);
            acc.w += w0*bf2f(u0.w) + w1*bf2f(u1.w) + w2*bf2f(u2.w) + w3*bf2f(u3.w);
        }
        for (; k < cnt; ++k) {
            int   sk = __shfl(src, k, 8);
            float nk = __shfl(nd, k, 8);
            ushort4 u = *(const ushort4*)&hb[(size_t)sk * 32 + lane * 4];
            float wgt = dn * nk;
            acc.x += wgt * bf2f(u.x); acc.y += wgt * bf2f(u.y);
            acc.z += wgt * bf2f(u.z); acc.w += wgt * bf2f(u.w);
        }
    }
    {   // self loop
        ushort4 u = *(const ushort4*)&hb[(size_t)r * 32 + lane * 4];
        float wgt = dn * dn;
        acc.x += wgt * bf2f(u.x); acc.y += wgt * bf2f(u.y);
        acc.z += wgt * bf2f(u.z); acc.w += wgt * bf2f(u.w);
    }
    *(float4*)&srow[ln][lane * 4] = acc;
    __syncthreads();

    int fq = tid & 31;
    int ng = tid >> 5;
    float a[4][4];
#pragma unroll
    for (int j = 0; j < 4; ++j)
#pragma unroll
        for (int q = 0; q < 4; ++q) a[j][q] = 0.f;
#pragma unroll
    for (int c = 0; c < 32; ++c) {
        float4 wvv = *(const float4*)&sw[c * 128 + fq * 4];
#pragma unroll
        for (int j = 0; j < 4; ++j) {
            float xc = srow[ng * 4 + j][c];
            a[j][0] += xc * wvv.x; a[j][1] += xc * wvv.y;
            a[j][2] += xc * wvv.z; a[j][3] += xc * wvv.w;
        }
    }
    float4 bv = *(const float4*)&bias[fq * 4];
#pragma unroll
    for (int j = 0; j < 4; ++j) {
        ushort4 o;
        o.x = f2bf(fmaxf(a[j][0] + bv.x, 0.f));
        o.y = f2bf(fmaxf(a[j][1] + bv.y, 0.f));
        o.z = f2bf(fmaxf(a[j][2] + bv.z, 0.f));
        o.w = f2bf(fmaxf(a[j][3] + bv.w, 0.f));
        *(ushort4*)&h16[(size_t)(nbase + ng * 4 + j) * 128 + fq * 4] = o;
    }
}

// =======================================================================
// lin2 via MFMA bf16: h2[N,128] = h1[N,128] @ W2 using precomputed W2^T bf16.
// Staging is now 16x ushort4 copies (was 64x scalar f32 + cvt).
// =======================================================================
__global__ __launch_bounds__(256) void k_lin2(const unsigned short* __restrict__ g16,
        const unsigned short* __restrict__ w2t, unsigned short* __restrict__ h16) {
    __shared__ unsigned short srow[64][136];
    __shared__ unsigned short swT[128][136];
    int tid = threadIdx.x;
    int nbase = blockIdx.x * 64;

    {   // stage A rows (64x128 bf16)
        const ushort4* src = (const ushort4*)(g16 + (size_t)nbase * 128);
#pragma unroll
        for (int i = 0; i < 8; ++i) {
            int idx = tid + i * 256;
            int row = idx >> 5, col4 = idx & 31;
            ushort4 v = src[idx];
            *(ushort4*)&srow[row][col4 * 4] = v;
        }
    }
    {   // stage W2^T (128x128 bf16) via vector copies
        const ushort4* src = (const ushort4*)w2t;
#pragma unroll
        for (int i = 0; i < 16; ++i) {
            int idx = tid + i * 256;          // 4096 ushort4 total
            int f = idx >> 5, c4 = idx & 31;
            ushort4 v = src[idx];
            *(ushort4*)&swT[f][c4 * 4] = v;
        }
    }
    __syncthreads();

    int wv  = tid >> 6;
    int lane = tid & 63;
    int m0 = wv * 16;
    int l15 = lane & 15;
    int quad = lane >> 4;
    f32x4 acc[8];
#pragma unroll
    for (int nt = 0; nt < 8; ++nt) acc[nt] = (f32x4){0.f, 0.f, 0.f, 0.f};
#pragma unroll
    for (int kc = 0; kc < 4; ++kc) {
        int k0 = kc * 32 + quad * 8;
        short8 a = *(const short8*)&srow[m0 + l15][k0];
#pragma unroll
        for (int nt = 0; nt < 8; ++nt) {
            short8 b = *(const short8*)&swT[nt * 16 + l15][k0];
            acc[nt] = __builtin_amdgcn_mfma_f32_16x16x32_bf16(a, b, acc[nt], 0, 0, 0);
        }
    }
#pragma unroll
    for (int nt = 0; nt < 8; ++nt) {
#pragma unroll
        for (int r = 0; r < 4; ++r) {
            int row = m0 + quad * 4 + r;
            int col = nt * 16 + l15;
            h16[(size_t)(nbase + row) * 128 + col] = f2bf(acc[nt][r]);
        }
    }
}

// ---- layer-2 gather (bf16 h) + self-loop + bias + relu + partial colsum [R12]
__global__ __launch_bounds__(256) void k_gather128(const int* __restrict__ rptr,
        const int* __restrict__ adj, const float* __restrict__ dis,
        const unsigned short* __restrict__ h, const float* __restrict__ bias,
        float* __restrict__ partial) {
    __shared__ float sred[8][128];
    int bid  = (blockIdx.x & 7) * 1024 + (blockIdx.x >> 3);  // XCD swizzle, 8192
    int tid  = threadIdx.x;
    int g    = tid >> 5;
    int lane = tid & 31;
    int node = bid * 8 + g;
    int b = node >> 9;
    int r = node & 511;
    const unsigned short* hb = h + (size_t)b * RR * 128;
    int s = rptr[r], e = rptr[r + 1];
    float dn = dis[r];
    float4 acc = make_float4(0.f, 0.f, 0.f, 0.f);
    for (int base = s; base < e; base += 32) {
        int j = base + lane;
        int src = 0; float nd = 0.f;
        if (j < e) { src = adj[j]; nd = dis[src]; }
        int cnt = min(32, e - base);
        int k = 0;
        for (; k + 4 <= cnt; k += 4) {
            int   s0 = __shfl(src, k, 32),     s1 = __shfl(src, k + 1, 32);
            int   s2 = __shfl(src, k + 2, 32), s3 = __shfl(src, k + 3, 32);
            float n0 = __shfl(nd, k, 32),      n1 = __shfl(nd, k + 1, 32);
            float n2 = __shfl(nd, k + 2, 32),  n3 = __shfl(nd, k + 3, 32);
            ushort4 u0 = *(const ushort4*)&hb[(size_t)s0 * 128 + lane * 4];
            ushort4 u1 = *(const ushort4*)&hb[(size_t)s1 * 128 + lane * 4];
            ushort4 u2 = *(const ushort4*)&hb[(size_t)s2 * 128 + lane * 4];
            ushort4 u3 = *(const ushort4*)&hb[(size_t)s3 * 128 + lane * 4];
            float w0 = dn * n0, w1 = dn * n1, w2 = dn * n2, w3 = dn * n3;
            acc.x += w0*bf2f(u0.x) + w1*bf2f(u1.x) + w2*bf2f(u2.x) + w3*bf2f(u3.x);
            acc.y += w0*bf2f(u0.y) + w1*bf2f(u1.y) + w2*bf2f(u2.y) + w3*bf2f(u3.y);
            acc.z += w0*bf2f(u0.z) + w1*bf2f(u1.z) + w2*bf2f(u2.z) + w3*bf2f(u3.z);
            acc.w += w0*bf2f(u0.w) + w1*bf2f(u1.w) + w2*bf2f(u2.w) + w3*bf2f(u3.w);
        }
        for (; k < cnt; ++k) {
            int   sk = __shfl(src, k, 32);
            float nk = __shfl(nd, k, 32);
            ushort4 u = *(const ushort4*)&hb[(size_t)sk * 128 + lane * 4];
            float wgt = dn * nk;
            acc.x += wgt * bf2f(u.x); acc.y += wgt * bf2f(u.y);
            acc.z += wgt * bf2f(u.z); acc.w += wgt * bf2f(u.w);
        }
    }
    ushort4 u = *(const ushort4*)&hb[(size_t)r * 128 + lane * 4];
    float wgt = dn * dn;
    float4 bv = *(const float4*)&bias[lane * 4];
    acc.x = fmaxf(acc.x + wgt * bf2f(u.x) + bv.x, 0.f);
    acc.y = fmaxf(acc.y + wgt * bf2f(u.y) + bv.y, 0.f);
    acc.z = fmaxf(acc.z + wgt * bf2f(u.z) + bv.z, 0.f);
    acc.w = fmaxf(acc.w + wgt * bf2f(u.w) + bv.w, 0.f);
    *(float4*)&sred[g][lane * 4] = acc;
    __syncthreads();
    if (tid < 128) {
        float ssum = 0.f;
#pragma unroll
        for (int j = 0; j < 8; ++j) ssum += sred[j][tid];
        partial[(size_t)bid * 128 + tid] = ssum;   // plain coalesced store
    }
}

// ---------------- fc: sum partials -> mean -> out = mean @ fw + fb [R12] ----
__global__ __launch_bounds__(128) void k_fc(const float* __restrict__ partial,
        const float* __restrict__ fw, const float* __restrict__ fb,
        float* __restrict__ out) {
    __shared__ float sm[HID];
    int b = blockIdx.x, f = threadIdx.x;
    float acc = 0.f;
#pragma unroll 8
    for (int j = 0; j < 64; ++j) acc += partial[(size_t)(b * 64 + j) * 128 + f];
    sm[f] = acc * (1.0f / RR);
    __syncthreads();
    if (f < NOUT) {
        float s = fb[f];
#pragma unroll
        for (int c = 0; c < HID; ++c) s += sm[c] * fw[c * NOUT + f];
        out[b * NOUT + f] = s;
    }
}

extern "C" void kernel_launch(void* const* d_in, const int* in_sizes, int n_in,
                              void* d_out, int out_size, void* d_ws, size_t ws_size,
                              hipStream_t stream) {
    const float* x   = (const float*)d_in[0];
    const int*   ei  = (const int*)d_in[1];
    const float* c1w = (const float*)d_in[2];
    const float* c1b = (const float*)d_in[3];
    const float* c2w = (const float*)d_in[4];
    const float* c2b = (const float*)d_in[5];
    const float* g1w = (const float*)d_in[6];
    const float* g1b = (const float*)d_in[7];
    const float* g2w = (const float*)d_in[8];
    const float* g2b = (const float*)d_in[9];
    const float* fw  = (const float*)d_in[10];
    const float* fb  = (const float*)d_in[11];
    float* out = (float*)d_out;
    int E  = in_sizes[1] / 2;   // total edges (1048576)
    int es = E / BB;            // edges per sample graph (8192)

    char* ws = (char*)d_ws;
    unsigned short* nodes16 = (unsigned short*)(ws);               // 4 MB  [N,32] bf16
    unsigned short* bufA16  = (unsigned short*)(ws + (4u << 20));  // 16 MB [N,128] bf16
    unsigned short* bufC16  = (unsigned short*)(ws + (20u << 20)); // 16 MB [N,128] bf16
    int*   rptr    = (int*)  (ws + (36u << 20));                   // [513]
    float* dis     = (float*)(ws + (36u << 20) + 4096);            // [512]
    int*   adj     = (int*)  (ws + (36u << 20) + 8192);            // 32 KB [es]
    unsigned short* w2t = (unsigned short*)(ws + (36u << 20) + 65536); // 32 KB
    float* partial = (float*)(ws + (37u << 20));                   // 4 MB [8192,128]

    // CSR + w2t (block 0, starts first) + fused temporal convs (blocks 1..1024)
    k_convs<<<BB * 8 + 1, 512, 0, stream>>>(x, c1w, c1b, c2w, c2b, nodes16,
                                            ei, E, es, rptr, dis, adj, g2w, w2t);

    // GCN layer 1: fused gather(32-dim bf16) + linear + bias + relu -> bf16
    k_gl1<<<NN / 32, 256, 0, stream>>>(rptr, adj, dis, nodes16, g1w, g1b, bufA16);

    // GCN layer 2: MFMA linear (precomputed W2^T), then gather -> partials
    k_lin2<<<NN / 64, 256, 0, stream>>>(bufA16, w2t, bufC16);
    k_gather128<<<NN / 8, 256, 0, stream>>>(rptr, adj, dis, bufC16, g2b, partial);

    // mean (from partials) + fc
    k_fc<<<BB, 128, 0, stream>>>(partial, fw, fb, out);
}